// Round 2
// baseline (697.036 us; speedup 1.0000x reference)
//
#include <hip/hip_runtime.h>
#include <math.h>

// Problem constants (from reference setup_inputs): B=4,H=16,S=8192,D=128
#define BH   64      // B*H
#define SEQ  8192
#define DIM  128
#define NB   16      // num_blocks = S / BLOCK_SIZE
#define BS   512     // BLOCK_SIZE

// ---------------------------------------------------------------------------
// Kernel 1: kmean_d[bh][nb][d] = mean over BS rows of k, double accumulation,
// stored as DOUBLE (K2 consumes it via wave-uniform scalar loads -> no cvt,
// no LDS). Fused: query_block_indices[s] = s >> 9.
// Grid: BH*NB = 1024 blocks, 256 threads. Coalesced float4 reads (memory-
// bound, ~45 us at 6.3 TB/s for 256 MB).
// ---------------------------------------------------------------------------
__global__ __launch_bounds__(256) void kmean_kernel(const float* __restrict__ k,
                                                    double* __restrict__ kmean_d,
                                                    int* __restrict__ qbi) {
  int gt = blockIdx.x * 256 + threadIdx.x;
  if (gt < SEQ) qbi[gt] = gt >> 9;

  int blk = blockIdx.x;            // 0..BH*NB-1
  int bh  = blk >> 4;
  int nb  = blk & 15;
  const float4* base = (const float4*)(k + ((size_t)bh * SEQ + (size_t)nb * BS) * DIM);
  int t  = threadIdx.x;
  int c4 = t & 31;                 // float4 column within row
  int r0 = t >> 5;                 // 0..7
  double a0 = 0, a1 = 0, a2 = 0, a3 = 0;
  for (int r = r0; r < BS; r += 8) {
    float4 v = base[r * 32 + c4];
    a0 += (double)v.x; a1 += (double)v.y; a2 += (double)v.z; a3 += (double)v.w;
  }
  __shared__ double red[8][32][4];
  red[r0][c4][0] = a0; red[r0][c4][1] = a1;
  red[r0][c4][2] = a2; red[r0][c4][3] = a3;
  __syncthreads();
  if (r0 == 0) {
    double s0 = 0, s1 = 0, s2 = 0, s3 = 0;
#pragma unroll
    for (int r = 0; r < 8; ++r) {
      s0 += red[r][c4][0]; s1 += red[r][c4][1];
      s2 += red[r][c4][2]; s3 += red[r][c4][3];
    }
    const double inv = 1.0 / (double)BS;    // exact power of two
    double2* dst = (double2*)kmean_d + ((size_t)(bh * NB + nb) * 32 + c4) * 2;
    double2 o0, o1;
    o0.x = s0 * inv; o0.y = s1 * inv;
    o1.x = s2 * inv; o1.y = s3 * inv;
    dst[0] = o0; dst[1] = o1;
  }
}

// ---------------------------------------------------------------------------
// Kernel 2: scores + causal mask + stable top-4. TWO queries per thread.
//
// vs previous round:
//  - k-operand comes from wave-uniform GLOBAL loads (s_load into SGPRs; the
//    1 MB kmean is L2-resident, ~9 KB re-read per block). This deletes all
//    ~544 LDS broadcast ds_read_b128 per wave that dominated the LDS pipe,
//    and the 16 KB kkd buffer. v_fma_f64 legally takes one SGPR-pair src.
//  - 2 queries/thread: halves wave count -> per-query staging cost halves;
//    two independent 8-FMA chains per block give FMA ILP.
//  - q staged per-wave via LDS transpose in 8-float chunks (coalesced 32 B
//    global segments; L2 makes the 128 B lines fully used across 4 adjacent
//    chunks). LDS write linear (conflict-free), read 2-way (free per m136).
//
// Grid: BH*SEQ/512 = 1024 blocks x 256 thr (4 waves x 128 queries).
// LDS: 16 KB (q staging only). ~125 VGPR -> 12-16 waves/CU.
// ---------------------------------------------------------------------------

// Stable top-4 on packed sortable u64 keys; low 4 bits = 15-n so exact ties
// (incl. shared -inf of masked blocks) break to lower n, matching
// jax.lax.top_k stable descending order. Macro (not function) so the ps/keys
// arrays keep compile-time indexing -> registers, never scratch.
#define TOPK_STORE(PS, QIDX)                                                   \
  {                                                                            \
    unsigned long long keys[NB];                                               \
_Pragma("unroll")                                                              \
    for (int n = 0; n < NB; ++n) {                                             \
      double v = (n <= qbs) ? PS[n] : -INFINITY;                               \
      long long u = __double_as_longlong(v);                                   \
      unsigned long long sk =                                                  \
          (unsigned long long)(u ^ ((u >> 63) | 0x8000000000000000LL));        \
      keys[n] = (sk & ~0xFULL) | (unsigned long long)(15 - n);                 \
    }                                                                          \
    int res[4];                                                                \
_Pragma("unroll")                                                              \
    for (int pp = 0; pp < 4; ++pp) {                                           \
      unsigned long long best = keys[0];                                       \
_Pragma("unroll")                                                              \
      for (int n = 1; n < NB; ++n) best = (keys[n] > best) ? keys[n] : best;   \
      res[pp] = 15 - (int)(best & 0xFULL);                                     \
_Pragma("unroll")                                                              \
      for (int n = 0; n < NB; ++n) keys[n] = (keys[n] == best) ? 0ULL : keys[n];\
    }                                                                          \
    *(int4*)(out + (size_t)(QIDX) * 4) = make_int4(res[0], res[1], res[2], res[3]); \
  }

__global__ __launch_bounds__(256) void score_topk_kernel(const float* __restrict__ q,
                                                         const double* __restrict__ kmean_d,
                                                         int* __restrict__ out) {
  __shared__ float4 qs[4][256];   // per-wave: 128 rows x 8-float chunk = 4 KB

  int t      = threadIdx.x;
  int qstart = blockIdx.x * 512;       // block covers one full query-block
  int bh     = qstart >> 13;
  int wave   = t >> 6;
  int lane   = t & 63;
  int qw     = qstart + wave * 128;    // wave's first query
  int qbs    = __builtin_amdgcn_readfirstlane((qw & (SEQ - 1)) >> 9);

  const double* kbh   = kmean_d + (size_t)bh * NB * DIM;   // wave-uniform
  const float4* qbase = (const float4*)(q + (size_t)qw * DIM);
  float4* myqs = qs[wave];             // wave-private: wave_barrier suffices

  int srow = lane >> 1;                // staging source row group (0..31)
  int sf   = lane & 1;                 // float4 within the 32 B chunk

  double ps0[NB], ps1[NB];
#pragma unroll
  for (int n = 0; n < NB; ++n) { ps0[n] = 0.0; ps1[n] = 0.0; }

  // prologue: chunk 0 loads (rows i*32+srow, floats [0,8))
  float4 ld[4];
#pragma unroll
  for (int i = 0; i < 4; ++i)
    ld[i] = qbase[(size_t)(i * 32 + srow) * 32 + sf];

  for (int c = 0; c < 16; ++c) {
    // stage chunk c: slot i*64+lane == row-major [128 rows][2 float4]
#pragma unroll
    for (int i = 0; i < 4; ++i) myqs[i * 64 + lane] = ld[i];
    __builtin_amdgcn_wave_barrier();

    // read own two rows' 8 floats, widen once
    float4 a0 = myqs[2 * lane];
    float4 a1 = myqs[2 * lane + 1];
    float4 b0 = myqs[2 * (lane + 64)];
    float4 b1 = myqs[2 * (lane + 64) + 1];
    double qa[8], qb[8];
    qa[0] = (double)a0.x; qa[1] = (double)a0.y; qa[2] = (double)a0.z; qa[3] = (double)a0.w;
    qa[4] = (double)a1.x; qa[5] = (double)a1.y; qa[6] = (double)a1.z; qa[7] = (double)a1.w;
    qb[0] = (double)b0.x; qb[1] = (double)b0.y; qb[2] = (double)b0.z; qb[3] = (double)b0.w;
    qb[4] = (double)b1.x; qb[5] = (double)b1.y; qb[6] = (double)b1.z; qb[7] = (double)b1.w;

    // issue next chunk's global loads under the FMA phase
    if (c < 15) {
#pragma unroll
      for (int i = 0; i < 4; ++i)
        ld[i] = qbase[(size_t)(i * 32 + srow) * 32 + (c + 1) * 2 + sf];
    }

    // accumulate: k operand via wave-uniform global loads (SGPR / s_load)
#pragma unroll
    for (int n = 0; n < NB; ++n) {
      if (n <= qbs) {                  // SALU branch (qbs is SGPR-uniform)
        const double* kr = kbh + n * DIM + c * 8;   // uniform address
        double x0 = ps0[n], x1 = ps1[n];
#pragma unroll
        for (int j = 0; j < 8; ++j) {
          double kv = kr[j];
          x0 = fma(qa[j], kv, x0);
          x1 = fma(qb[j], kv, x1);
        }
        ps0[n] = x0; ps1[n] = x1;
      }
    }
    __builtin_amdgcn_wave_barrier();   // next chunk's writes stay after reads
  }

  TOPK_STORE(ps0, qw + lane);
  TOPK_STORE(ps1, qw + 64 + lane);
}

// ---------------------------------------------------------------------------
extern "C" void kernel_launch(void* const* d_in, const int* in_sizes, int n_in,
                              void* d_out, int out_size, void* d_ws, size_t ws_size,
                              hipStream_t stream) {
  (void)in_sizes; (void)n_in; (void)out_size; (void)ws_size;
  const float* q = (const float*)d_in[0];
  const float* k = (const float*)d_in[1];
  double* kmean_d = (double*)d_ws;             // BH*NB*DIM doubles = 1 MB
  int*    out     = (int*)d_out;
  int*    qbi     = out + (size_t)BH * SEQ * 4;

  hipLaunchKernelGGL(kmean_kernel, dim3(BH * NB), dim3(256), 0, stream,
                     k, kmean_d, qbi);
  hipLaunchKernelGGL(score_topk_kernel, dim3(BH * SEQ / 512), dim3(256), 0, stream,
                     q, kmean_d, out);
}

// Round 3
// 608.699 us; speedup vs baseline: 1.1451x; 1.1451x over previous
//
#include <hip/hip_runtime.h>
#include <math.h>

// Problem constants (from reference setup_inputs): B=4,H=16,S=8192,D=128
#define BH   64      // B*H
#define SEQ  8192
#define DIM  128
#define NB   16      // num_blocks = S / BLOCK_SIZE
#define BS   512     // BLOCK_SIZE

// ---------------------------------------------------------------------------
// Kernel 1: kmean_d[bh][nb][d] = mean over BS rows of k, double accumulation,
// stored as DOUBLE (K2 consumes it via wave-uniform scalar loads). Fused:
// query_block_indices[s] = s >> 9. Memory-bound (~50 us, near-roofline).
// Bitwise identical to the passing rounds.
// ---------------------------------------------------------------------------
__global__ __launch_bounds__(256) void kmean_kernel(const float* __restrict__ k,
                                                    double* __restrict__ kmean_d,
                                                    int* __restrict__ qbi) {
  int gt = blockIdx.x * 256 + threadIdx.x;
  if (gt < SEQ) qbi[gt] = gt >> 9;

  int blk = blockIdx.x;            // 0..BH*NB-1
  int bh  = blk >> 4;
  int nb  = blk & 15;
  const float4* base = (const float4*)(k + ((size_t)bh * SEQ + (size_t)nb * BS) * DIM);
  int t  = threadIdx.x;
  int c4 = t & 31;                 // float4 column within row
  int r0 = t >> 5;                 // 0..7
  double a0 = 0, a1 = 0, a2 = 0, a3 = 0;
  for (int r = r0; r < BS; r += 8) {
    float4 v = base[r * 32 + c4];
    a0 += (double)v.x; a1 += (double)v.y; a2 += (double)v.z; a3 += (double)v.w;
  }
  __shared__ double red[8][32][4];
  red[r0][c4][0] = a0; red[r0][c4][1] = a1;
  red[r0][c4][2] = a2; red[r0][c4][3] = a3;
  __syncthreads();
  if (r0 == 0) {
    double s0 = 0, s1 = 0, s2 = 0, s3 = 0;
#pragma unroll
    for (int r = 0; r < 8; ++r) {
      s0 += red[r][c4][0]; s1 += red[r][c4][1];
      s2 += red[r][c4][2]; s3 += red[r][c4][3];
    }
    const double inv = 1.0 / (double)BS;    // exact power of two
    double2* dst = (double2*)kmean_d + ((size_t)(bh * NB + nb) * 32 + c4) * 2;
    double2 o0, o1;
    o0.x = s0 * inv; o0.y = s1 * inv;
    o1.x = s2 * inv; o1.y = s3 * inv;
    dst[0] = o0; dst[1] = o1;
  }
}

// ---------------------------------------------------------------------------
// Kernel 2: scores + causal mask + stable top-4. ONE query per thread.
//
// Fixes vs round 2 (which spilled its accumulator arrays to scratch and had
// 16-way LDS read conflicts):
//  - accumulators are 16 NAMED double scalars p0..p15, each updated in its
//    own literal-index guarded block: nothing for the compiler to demote or
//    re-roll. (Round 2: ps arrays -> scratch, 258 MB of HBM spill writes.)
//  - LDS transpose buffer: [64 rows][20 words] (16 floats + 4 pad, 80 B row
//    stride). Bank math: quad-start (20*l + 4*c) mod 32 takes each of the 8
//    values {0,4,..,28} for exactly 8 lanes -> every bank gets exactly 8
//    words per b128 access = port-limit minimum, for BOTH the write pattern
//    (rows i*16+(l>>2), slot l&3) and the read pattern (row l, slots 0..3).
//    80 B stride keeps every float4 slot 16 B aligned (80r+16c).
//  - k operand via wave-uniform loads (scalarized to s_load; kmean L2/L1
//    resident) -> no LDS and no per-FMA cvt on the k side.
//
// Accumulation order per (q,n): d ascending 0..127, fp64 -> bitwise same
// scores as all passing rounds; sortable-key top-4 unchanged.
//
// Grid: BH*SEQ/256 = 2048 blocks x 256 thr (4 waves x 64 queries).
// LDS: 4 waves x 5120 B = 20 KB. Est ~120 VGPR, no spill.
// ---------------------------------------------------------------------------

// Per-block accumulate: literal N, named scalar accumulator P.
// qbs is wave-uniform (SGPR) -> s_cmp + s_cbranch around the body.
#define ACC(N, P)                                                              \
  if (qbs >= (N)) {                                                            \
    const double* kr_##P = kbh + (N) * DIM + c * 16;                           \
    _Pragma("unroll")                                                          \
    for (int j = 0; j < 16; ++j) P = fma(qd[j], kr_##P[j], P);                 \
  }

__global__ __launch_bounds__(256) void score_topk_kernel(const float* __restrict__ q,
                                                         const double* __restrict__ kmean_d,
                                                         int* __restrict__ out) {
  __shared__ float qs[4][64 * 20];      // per-wave 64 rows x (16 floats + pad)

  int t      = threadIdx.x;
  int qstart = blockIdx.x * 256;
  int bh     = qstart >> 13;
  int wave   = t >> 6;
  int lane   = t & 63;
  int qw     = qstart + wave * 64;      // wave's first query
  int qbs    = __builtin_amdgcn_readfirstlane((qw & (SEQ - 1)) >> 9);

  const double* kbh   = kmean_d + (size_t)bh * NB * DIM;   // wave-uniform
  const float4* qbase = (const float4*)(q + (size_t)qw * DIM);
  float* myqs = qs[wave];               // wave-private: wave_barrier suffices

  int sr = lane >> 2;                   // staging source row group (0..15)
  int sc = lane & 3;                    // float4 slot within 16-float chunk

  double p0 = 0, p1 = 0, p2 = 0, p3 = 0, p4 = 0, p5 = 0, p6 = 0, p7 = 0;
  double p8 = 0, p9 = 0, p10 = 0, p11 = 0, p12 = 0, p13 = 0, p14 = 0, p15 = 0;

  // prologue: chunk 0 (float4 cols 0..3) for rows i*16+sr
  float4 ld[4];
#pragma unroll
  for (int i = 0; i < 4; ++i)
    ld[i] = qbase[(size_t)(i * 16 + sr) * 32 + sc];

  for (int c = 0; c < 8; ++c) {         // 8 chunks x 16 floats = DIM
    // stage chunk c: row r at word 20r, slot sc at +4*sc (aligned, balanced)
#pragma unroll
    for (int i = 0; i < 4; ++i)
      *(float4*)&myqs[(i * 16 + sr) * 20 + 4 * sc] = ld[i];
    __builtin_amdgcn_wave_barrier();

    // read own row (bank-balanced b128 x4), widen once
    float4 f0 = *(const float4*)&myqs[lane * 20 + 0];
    float4 f1 = *(const float4*)&myqs[lane * 20 + 4];
    float4 f2 = *(const float4*)&myqs[lane * 20 + 8];
    float4 f3 = *(const float4*)&myqs[lane * 20 + 12];
    double qd[16];
    qd[0]  = (double)f0.x; qd[1]  = (double)f0.y; qd[2]  = (double)f0.z; qd[3]  = (double)f0.w;
    qd[4]  = (double)f1.x; qd[5]  = (double)f1.y; qd[6]  = (double)f1.z; qd[7]  = (double)f1.w;
    qd[8]  = (double)f2.x; qd[9]  = (double)f2.y; qd[10] = (double)f2.z; qd[11] = (double)f2.w;
    qd[12] = (double)f3.x; qd[13] = (double)f3.y; qd[14] = (double)f3.z; qd[15] = (double)f3.w;

    // issue next chunk's global loads under the FMA phase
    if (c < 7) {
#pragma unroll
      for (int i = 0; i < 4; ++i)
        ld[i] = qbase[(size_t)(i * 16 + sr) * 32 + 4 * (c + 1) + sc];
    }

    ACC(0,  p0)  ACC(1,  p1)  ACC(2,  p2)  ACC(3,  p3)
    ACC(4,  p4)  ACC(5,  p5)  ACC(6,  p6)  ACC(7,  p7)
    ACC(8,  p8)  ACC(9,  p9)  ACC(10, p10) ACC(11, p11)
    ACC(12, p12) ACC(13, p13) ACC(14, p14) ACC(15, p15)

    __builtin_amdgcn_wave_barrier();    // keep next writes after this read
  }

  // ---- stable top-4 on packed sortable u64 keys (unchanged semantics) ----
  double psv[NB] = {p0, p1, p2,  p3,  p4,  p5,  p6,  p7,
                    p8, p9, p10, p11, p12, p13, p14, p15};
  unsigned long long keys[NB];
#pragma unroll
  for (int n = 0; n < NB; ++n) {
    double v = (n <= qbs) ? psv[n] : -INFINITY;
    long long u = __double_as_longlong(v);
    unsigned long long sk =
        (unsigned long long)(u ^ ((u >> 63) | 0x8000000000000000LL));
    keys[n] = (sk & ~0xFULL) | (unsigned long long)(15 - n);
  }
  int res[4];
#pragma unroll
  for (int pp = 0; pp < 4; ++pp) {
    unsigned long long best = keys[0];
#pragma unroll
    for (int n = 1; n < NB; ++n) best = (keys[n] > best) ? keys[n] : best;
    res[pp] = 15 - (int)(best & 0xFULL);
#pragma unroll
    for (int n = 0; n < NB; ++n) keys[n] = (keys[n] == best) ? 0ULL : keys[n];
  }
  *(int4*)(out + (size_t)(qw + lane) * 4) = make_int4(res[0], res[1], res[2], res[3]);
}

// ---------------------------------------------------------------------------
extern "C" void kernel_launch(void* const* d_in, const int* in_sizes, int n_in,
                              void* d_out, int out_size, void* d_ws, size_t ws_size,
                              hipStream_t stream) {
  (void)in_sizes; (void)n_in; (void)out_size; (void)ws_size;
  const float* q = (const float*)d_in[0];
  const float* k = (const float*)d_in[1];
  double* kmean_d = (double*)d_ws;             // BH*NB*DIM doubles = 1 MB
  int*    out     = (int*)d_out;
  int*    qbi     = out + (size_t)BH * SEQ * 4;

  hipLaunchKernelGGL(kmean_kernel, dim3(BH * NB), dim3(256), 0, stream,
                     k, kmean_d, qbi);
  hipLaunchKernelGGL(score_topk_kernel, dim3(BH * SEQ / 256), dim3(256), 0, stream,
                     q, kmean_d, out);
}